// Round 7
// baseline (36145.758 us; speedup 1.0000x reference)
//
#include <hip/hip_runtime.h>
#include <math.h>

#define TT 2048
#define BB 32
#define HH 512

// ---------------- input-projection GEMM: OUT[r,:] = X[r,:]@W + bias ----------------
// 32 rows per WG staged in LDS; safe for in-place X==OUT (each WG reads only its own
// rows, fully staged before any write). Near the fp32 VALU roofline for this shape.
template<int K>
__global__ void __launch_bounds__(256)
ih_gemm(const float* X, const float* __restrict__ W,
        const float* __restrict__ bias, float* OUT)
{
    __shared__ float xt[32][K];
    const int wg  = (int)blockIdx.x;
    const int tid = (int)threadIdx.x;
    const long row0 = (long)wg * 32;

    {   // stage 32 rows of X (coalesced float4)
        const float4* Xv = (const float4*)(X + row0 * K);
        float4* xtv = (float4*)(&xt[0][0]);
        const int n4 = 8 * K;  // 32*K/4
        for (int i = tid; i < n4; i += 256) xtv[i] = Xv[i];
    }
    __syncthreads();

    const int j2 = tid * 2;              // thread owns cols j2, j2+1
    float acc0[32], acc1[32];
    #pragma unroll
    for (int r = 0; r < 32; ++r) { acc0[r] = 0.f; acc1[r] = 0.f; }

    for (int k = 0; k < K; k += 4) {
        const float2 w0 = *(const float2*)&W[(k+0)*HH + j2];
        const float2 w1 = *(const float2*)&W[(k+1)*HH + j2];
        const float2 w2 = *(const float2*)&W[(k+2)*HH + j2];
        const float2 w3 = *(const float2*)&W[(k+3)*HH + j2];
        #pragma unroll
        for (int r = 0; r < 32; ++r) {
            const float4 xv = *(const float4*)&xt[r][k];   // LDS broadcast (free)
            acc0[r] += xv.x*w0.x + xv.y*w1.x + xv.z*w2.x + xv.w*w3.x;
            acc1[r] += xv.x*w0.y + xv.y*w1.y + xv.z*w2.y + xv.w*w3.y;
        }
    }
    const float2 bv = *(const float2*)&bias[j2];
    #pragma unroll
    for (int r = 0; r < 32; ++r) {
        float2 o; o.x = acc0[r] + bv.x; o.y = acc1[r] + bv.y;
        *(float2*)&OUT[(row0 + r) * HH + j2] = o;
    }
}

// ---- 64-lane sum via DPP (VALU pipe only). ctrl/rmask must be constexpr ->
// template parameters (round-6 compile fix: builtin requires constant integers).
template<int CTRL, int RMASK>
static __device__ __forceinline__ float dpp_add(float s) {
    int t = __builtin_amdgcn_update_dpp(0, __float_as_int(s), CTRL, RMASK, 0xF, true);
    return s + __int_as_float(t);
}
static __device__ __forceinline__ float wave_sum64(float v) {
    v = dpp_add<0x111, 0xF>(v);   // row_shr:1
    v = dpp_add<0x112, 0xF>(v);   // row_shr:2
    v = dpp_add<0x114, 0xF>(v);   // row_shr:4
    v = dpp_add<0x118, 0xF>(v);   // row_shr:8  -> lane 15 of each 16-row = row total
    v = dpp_add<0x142, 0xA>(v);   // row_bcast:15 into rows 1,3
    v = dpp_add<0x143, 0xC>(v);   // row_bcast:31 into rows 2,3 -> lane 63 = wave total
    return v;
}

// ---------------- persistent recurrence: seq[c,t,:] : pre -> h, in-place ----------------
// Wave-autonomous: chain c has 64 waves (8 WGs x 8). Wave gw owns output cols
// [gw*8, gw*8+8); lane l owns k in [8l, 8l+8) -> an 8x8 W block in 16 contiguous
// float4s (64 VGPRs). h is lane-local (no readlane); k-reduce is a 6-stage DPP tree.
// NO LDS, NO __syncthreads anywhere -> the round-3 barrier/WAR hazard class is gone.
//
// amdgpu_waves_per_eu(2,2): clamps the allocator's occupancy TARGET (launch_bounds'
// 2nd arg is only a min; rounds 2-5 showed the allocator remats/reloads W from
// L2-scratch to chase max occupancy -> VGPR_Count 44-48, +400cy/step on the MAC).
//
// Comm per step: producer wave's 8 tail lanes publish 8B packed {tag:32|f32:32}
// (64B contiguous line); consumer lane l polls its own 8 contiguous slots (exactly
// one producer wave's line). Relaxed agent-scope 8B atomics: single-copy atomicity
// replaces all fences (round-1 killer). Double-buffered by t&1.
//
// Overwrite/lap safety (wave-granular tag-chain, same induction as rounds 4-5):
// a wave reaches step t only after consuming h[t-1] from ALL waves, which each
// published h[t-1] only after consuming h[t-2] -> no slot holding a still-needed
// tag can be overwritten, and a stuck poller blocks its producers from lapping.
__global__ void __attribute__((amdgpu_flat_work_group_size(512, 512),
                               amdgpu_waves_per_eu(2, 2)))
rnn_recur(const float* __restrict__ Whh,
          float* __restrict__ seq, float* __restrict__ hTout,
          unsigned long long* __restrict__ hb2, unsigned int tagbase)
{
    const int bid  = (int)blockIdx.x;
    const int c    = bid & 31;            // chain == batch row
    const int x    = bid >> 5;            // WG index within chain (0..7)
    const int tid  = (int)threadIdx.x;
    const int lane = tid & 63;
    const int w    = tid >> 6;
    const int gw   = (x << 3) + w;        // global wave id in chain: 0..63
    const int c0   = gw << 3;             // my wave's 8 output cols
    const int k0   = lane << 3;           // my lane's 8 k indices

    // ---- W block: rows k0..k0+7, cols c0..c0+7, as 16 contiguous float4s ----
    float4 wA0,wA1,wA2,wA3,wA4,wA5,wA6,wA7;   // cols c0..c0+3
    float4 wB0,wB1,wB2,wB3,wB4,wB5,wB6,wB7;   // cols c0+4..c0+7
#define LOADW(j) do { \
        wA##j = *(const float4*)&Whh[(long)(k0 + j) * HH + c0]; \
        wB##j = *(const float4*)&Whh[(long)(k0 + j) * HH + c0 + 4]; } while (0)
    LOADW(0); LOADW(1); LOADW(2); LOADW(3);
    LOADW(4); LOADW(5); LOADW(6); LOADW(7);
#undef LOADW
#define PINW(v) asm volatile("" : "+v"(v.x), "+v"(v.y), "+v"(v.z), "+v"(v.w))
    PINW(wA0); PINW(wA1); PINW(wA2); PINW(wA3);
    PINW(wA4); PINW(wA5); PINW(wA6); PINW(wA7);
    PINW(wB0); PINW(wB1); PINW(wB2); PINW(wB3);
    PINW(wB4); PINW(wB5); PINW(wB6); PINW(wB7);
#undef PINW

    unsigned long long* hbc = hb2 + c * (2 * HH);   // [2][512] packed {tag|val}
    float* rowbase = seq + (long)c * TT * HH;

    float h0=0.f,h1=0.f,h2=0.f,h3=0.f,h4=0.f,h5=0.f,h6=0.f,h7=0.f;
    float pre_cur = 0.f;
    if (lane < 8) pre_cur = rowbase[c0 + lane];     // pre[c,0,c0+lane]

    for (int t = 0; t < TT; ++t) {
        if (t > 0) {
            // poll my 8 slots of h[t-1] (all produced by wave gw==lane of this chain)
            const unsigned want = tagbase + (unsigned)t;
            unsigned long long* sl = hbc + (((t - 1) & 1) << 9) + k0;
            unsigned long long p0,p1,p2,p3,p4,p5,p6,p7;
            do {
                p0 = __hip_atomic_load(sl+0, __ATOMIC_RELAXED, __HIP_MEMORY_SCOPE_AGENT);
                p1 = __hip_atomic_load(sl+1, __ATOMIC_RELAXED, __HIP_MEMORY_SCOPE_AGENT);
                p2 = __hip_atomic_load(sl+2, __ATOMIC_RELAXED, __HIP_MEMORY_SCOPE_AGENT);
                p3 = __hip_atomic_load(sl+3, __ATOMIC_RELAXED, __HIP_MEMORY_SCOPE_AGENT);
                p4 = __hip_atomic_load(sl+4, __ATOMIC_RELAXED, __HIP_MEMORY_SCOPE_AGENT);
                p5 = __hip_atomic_load(sl+5, __ATOMIC_RELAXED, __HIP_MEMORY_SCOPE_AGENT);
                p6 = __hip_atomic_load(sl+6, __ATOMIC_RELAXED, __HIP_MEMORY_SCOPE_AGENT);
                p7 = __hip_atomic_load(sl+7, __ATOMIC_RELAXED, __HIP_MEMORY_SCOPE_AGENT);
            } while ((unsigned)(p0 >> 32) != want || (unsigned)(p1 >> 32) != want ||
                     (unsigned)(p2 >> 32) != want || (unsigned)(p3 >> 32) != want ||
                     (unsigned)(p4 >> 32) != want || (unsigned)(p5 >> 32) != want ||
                     (unsigned)(p6 >> 32) != want || (unsigned)(p7 >> 32) != want);
            h0 = __uint_as_float((unsigned)p0); h1 = __uint_as_float((unsigned)p1);
            h2 = __uint_as_float((unsigned)p2); h3 = __uint_as_float((unsigned)p3);
            h4 = __uint_as_float((unsigned)p4); h5 = __uint_as_float((unsigned)p5);
            h6 = __uint_as_float((unsigned)p6); h7 = __uint_as_float((unsigned)p7);
        }

        // MAC: acc_i = sum_j h[k0+j] * W[k0+j][c0+i]  (64 fmac, all operands in VGPRs)
        float a0=0.f,a1=0.f,a2=0.f,a3=0.f,a4=0.f,a5=0.f,a6=0.f,a7=0.f;
#define MACJ(j) do { \
        a0 = fmaf(h##j, wA##j.x, a0); a1 = fmaf(h##j, wA##j.y, a1); \
        a2 = fmaf(h##j, wA##j.z, a2); a3 = fmaf(h##j, wA##j.w, a3); \
        a4 = fmaf(h##j, wB##j.x, a4); a5 = fmaf(h##j, wB##j.y, a5); \
        a6 = fmaf(h##j, wB##j.z, a6); a7 = fmaf(h##j, wB##j.w, a7); } while (0)
        MACJ(0); MACJ(1); MACJ(2); MACJ(3);
        MACJ(4); MACJ(5); MACJ(6); MACJ(7);
#undef MACJ
        // k-reduce over 64 lanes (DPP, VALU pipe; totals land in lane 63)
        a0 = wave_sum64(a0); a1 = wave_sum64(a1);
        a2 = wave_sum64(a2); a3 = wave_sum64(a3);
        a4 = wave_sum64(a4); a5 = wave_sum64(a5);
        a6 = wave_sum64(a6); a7 = wave_sum64(a7);
        const float s0 = __uint_as_float(__builtin_amdgcn_readlane(__float_as_uint(a0), 63));
        const float s1 = __uint_as_float(__builtin_amdgcn_readlane(__float_as_uint(a1), 63));
        const float s2 = __uint_as_float(__builtin_amdgcn_readlane(__float_as_uint(a2), 63));
        const float s3 = __uint_as_float(__builtin_amdgcn_readlane(__float_as_uint(a3), 63));
        const float s4 = __uint_as_float(__builtin_amdgcn_readlane(__float_as_uint(a4), 63));
        const float s5 = __uint_as_float(__builtin_amdgcn_readlane(__float_as_uint(a5), 63));
        const float s6 = __uint_as_float(__builtin_amdgcn_readlane(__float_as_uint(a6), 63));
        const float s7 = __uint_as_float(__builtin_amdgcn_readlane(__float_as_uint(a7), 63));

        if (lane < 8) {   // tail: 8 lanes finish cols c0..c0+7
            const float mv = (lane & 4) ? ((lane & 2) ? ((lane & 1) ? s7 : s6)
                                                      : ((lane & 1) ? s5 : s4))
                                        : ((lane & 2) ? ((lane & 1) ? s3 : s2)
                                                      : ((lane & 1) ? s1 : s0));
            const float z  = mv + pre_cur;
            // tanh(z) = 1 - 2/(e^{2z}+1); exp-based, ~2e-7 abs err, inf-safe
            const float e  = __expf(2.0f * z);
            const float hv = 1.0f - 2.0f / (e + 1.0f);
            if (t + 1 < TT) {
                // publish FIRST: cross-wave critical path (8 lanes -> 64B line)
                const unsigned long long pk =
                    ((unsigned long long)(tagbase + (unsigned)(t + 1)) << 32)
                    | (unsigned long long)__float_as_uint(hv);
                __hip_atomic_store(hbc + (((t & 1) << 9) + c0 + lane), pk,
                                   __ATOMIC_RELAXED, __HIP_MEMORY_SCOPE_AGENT);
                rowbase[(long)t * HH + c0 + lane] = hv;
                pre_cur = rowbase[(long)(t + 1) * HH + c0 + lane];  // prefetch
            } else {
                rowbase[(long)t * HH + c0 + lane] = hv;
                hTout[(c << 9) + c0 + lane] = hv;
            }
        }
    }
}

extern "C" void kernel_launch(void* const* d_in, const int* in_sizes, int n_in,
                              void* d_out, int out_size, void* d_ws, size_t ws_size,
                              hipStream_t stream) {
    const float* x    = (const float*)d_in[0];
    const float* Wih0 = (const float*)d_in[1];
    const float* Whh0 = (const float*)d_in[2];
    const float* b0   = (const float*)d_in[3];
    const float* Wih1 = (const float*)d_in[4];
    const float* Whh1 = (const float*)d_in[5];
    const float* b1   = (const float*)d_in[6];

    float* out = (float*)d_out;                       // [B,T,H] main + [2,B,H] tail
    float* hT  = out + (size_t)BB * TT * HH;

    // ws: [0, 256K) = hb2 packed {tag|value} broadcast buffer, 32 chains x 2 x 512 x 8B
    unsigned long long* hb2 = (unsigned long long*)d_ws;
    // Clear tags every call: graph replays reuse ws un-poisoned, and a stale tag from
    // the previous replay would exactly match this replay's wanted tag.
    (void)hipMemsetAsync(d_ws, 0, BB * 2 * HH * sizeof(unsigned long long), stream);

    // 1) pre0 = x @ W_ih0 + b0   -> d_out main region (scratch)
    ih_gemm<256><<<dim3((BB * TT) / 32), dim3(256), 0, stream>>>(x, Wih0, b0, out);
    // 2) layer-0 recurrence, in-place pre0 -> h0; hT[0] tail  (tags 1..2047)
    rnn_recur<<<dim3(256), dim3(512), 0, stream>>>(Whh0, out, hT, hb2, 0u);
    // 3) pre1 = h0 @ W_ih1 + b1, in-place
    ih_gemm<512><<<dim3((BB * TT) / 32), dim3(256), 0, stream>>>(out, Wih1, b1, out);
    // 4) layer-1 recurrence, in-place pre1 -> h1 (final out); hT[1] tail (tags 4097..6143)
    rnn_recur<<<dim3(256), dim3(512), 0, stream>>>(Whh1, out, hT + BB * HH, hb2, 4096u);
}

// Round 8
// 5585.733 us; speedup vs baseline: 6.4711x; 6.4711x over previous
//
#include <hip/hip_runtime.h>
#include <math.h>

#define TT 2048
#define BB 32
#define HH 512

// ---------------- input-projection GEMM: OUT[r,:] = X[r,:]@W + bias ----------------
// 32 rows per WG staged in LDS; safe for in-place X==OUT (each WG reads only its own
// rows, fully staged before any write).
template<int K>
__global__ void __launch_bounds__(256)
ih_gemm(const float* X, const float* __restrict__ W,
        const float* __restrict__ bias, float* OUT)
{
    __shared__ float xt[32][K];
    const int wg  = (int)blockIdx.x;
    const int tid = (int)threadIdx.x;
    const long row0 = (long)wg * 32;

    {   // stage 32 rows of X (coalesced float4)
        const float4* Xv = (const float4*)(X + row0 * K);
        float4* xtv = (float4*)(&xt[0][0]);
        const int n4 = 8 * K;  // 32*K/4
        for (int i = tid; i < n4; i += 256) xtv[i] = Xv[i];
    }
    __syncthreads();

    const int j2 = tid * 2;              // thread owns cols j2, j2+1
    float acc0[32], acc1[32];
    #pragma unroll
    for (int r = 0; r < 32; ++r) { acc0[r] = 0.f; acc1[r] = 0.f; }

    for (int k = 0; k < K; k += 4) {
        const float2 w0 = *(const float2*)&W[(k+0)*HH + j2];
        const float2 w1 = *(const float2*)&W[(k+1)*HH + j2];
        const float2 w2 = *(const float2*)&W[(k+2)*HH + j2];
        const float2 w3 = *(const float2*)&W[(k+3)*HH + j2];
        #pragma unroll
        for (int r = 0; r < 32; ++r) {
            const float4 xv = *(const float4*)&xt[r][k];   // LDS broadcast (free)
            acc0[r] += xv.x*w0.x + xv.y*w1.x + xv.z*w2.x + xv.w*w3.x;
            acc1[r] += xv.x*w0.y + xv.y*w1.y + xv.z*w2.y + xv.w*w3.y;
        }
    }
    const float2 bv = *(const float2*)&bias[j2];
    #pragma unroll
    for (int r = 0; r < 32; ++r) {
        float2 o; o.x = acc0[r] + bv.x; o.y = acc1[r] + bv.y;
        *(float2*)&OUT[(row0 + r) * HH + j2] = o;
    }
}

// ---------------- persistent recurrence: seq[c,t,:] : pre -> h, in-place ----------------
// Round-5 topology (PROVEN correct + lowest comm cost: 1 poll/thread/step, fan-in 1
// producer WG per consumer wave) + round-7 residency recipe (PROVEN: VGPR 88, no spill):
// amdgpu_waves_per_eu(2,2) clamps the allocator's occupancy TARGET so the pinned W
// stays in VGPRs; __launch_bounds__' 2nd arg is only a floor (rounds 2-5: VGPR 44-48,
// W re-read from L2-scratch every step). Round 7's wave-autonomous layout regressed 7x
// from 8x poll volume + fan-in 64 -> reverted to this topology.
//
// 8 WGs per chain; wave w == k-group w; lane l of wave w holds h[w*64+l] in hreg,
// broadcast via readlane. W slice in 16 named float4 SSA values (64 VGPRs).
//
// Cross-WG exchange per step: 8-byte relaxed agent-scope atomic {tag:32 | f32:32},
// double-buffered by t&1; consumers poll their own element until the tag matches. 8B
// single-copy atomicity replaces all fences (round-1 killer: agent fences = L2 flushes).
//
// ONE __syncthreads per step + LDS partials double-buffered by parity (round-3 race
// fix): distance-1 WAR goes to the other parity buffer; distance-2 is ordered by the
// barrier (wave 0 reaches barrier(t+1) only after its iter-t reduce reads).
//
// hb2 slot-overwrite safety (tag-chain): a WG overwrites a slot (tag t -> t+2) only
// after observing tag t+1 from ALL WGs, which requires every WG's waves to have
// consumed tag t. Disjoint per-layer tag ranges + memset-per-call kill replay staleness.
__global__ void __attribute__((amdgpu_flat_work_group_size(512, 512),
                               amdgpu_waves_per_eu(2, 2)))
rnn_recur(const float* __restrict__ Whh,
          float* __restrict__ seq, float* __restrict__ hTout,
          unsigned long long* __restrict__ hb2, unsigned int tagbase)
{
    __shared__ float lds_part[2][8][64];   // [parity][wave][lane]
    const int bid  = (int)blockIdx.x;
    const int c    = bid & 31;      // chain == batch; all 8 slices of chain c share bid%8
    const int x    = bid >> 5;      // slice 0..7
    const int tid  = (int)threadIdx.x;
    const int lane = tid & 63;
    const int w    = tid >> 6;      // wave id == k-group
    const int J    = (x << 6) + lane;

    // ---- W slice as 16 named float4 SSA values (64 VGPRs) ----
    const long wb = (long)(w << 6) * HH + J;   // &Whh[(w*64 + kk)*HH + J], kk stride HH
    float4 wv0, wv1, wv2, wv3, wv4, wv5, wv6, wv7,
           wv8, wv9, wv10, wv11, wv12, wv13, wv14, wv15;
#define LOADW(q) do { \
        wv##q.x = Whh[wb + (4*q+0)*HH]; wv##q.y = Whh[wb + (4*q+1)*HH]; \
        wv##q.z = Whh[wb + (4*q+2)*HH]; wv##q.w = Whh[wb + (4*q+3)*HH]; } while (0)
    LOADW(0);  LOADW(1);  LOADW(2);  LOADW(3);
    LOADW(4);  LOADW(5);  LOADW(6);  LOADW(7);
    LOADW(8);  LOADW(9);  LOADW(10); LOADW(11);
    LOADW(12); LOADW(13); LOADW(14); LOADW(15);
#undef LOADW
#define PINW(q) asm volatile("" : "+v"(wv##q.x), "+v"(wv##q.y), "+v"(wv##q.z), "+v"(wv##q.w))
    PINW(0);  PINW(1);  PINW(2);  PINW(3);
    PINW(4);  PINW(5);  PINW(6);  PINW(7);
    PINW(8);  PINW(9);  PINW(10); PINW(11);
    PINW(12); PINW(13); PINW(14); PINW(15);
#undef PINW

    unsigned long long* hbc = hb2 + c * (2 * HH);   // [2][512] packed {tag|val}
    float* rowbase = seq + (long)c * TT * HH;

    float hreg = 0.f;                               // h[t-1][w*64+lane]; t=0 -> zeros
    float pre_cur = 0.f;
    if (tid < 64) pre_cur = rowbase[J];             // pre[c,0,J] (only wave 0 uses it)

    for (int t = 0; t < TT; ++t) {
        const int p = t & 1;
        if (t > 0) {
            // wait for my element of h[t-1] (produced by WG w of this chain)
            const unsigned int want = tagbase + (unsigned)t;
            unsigned long long* myslot = hbc + (((t - 1) & 1) << 9) + (w << 6) + lane;
            unsigned long long pk = __hip_atomic_load(myslot, __ATOMIC_RELAXED, __HIP_MEMORY_SCOPE_AGENT);
            while ((unsigned)(pk >> 32) != want)
                pk = __hip_atomic_load(myslot, __ATOMIC_RELAXED, __HIP_MEMORY_SCOPE_AGENT);
            hreg = __uint_as_float((unsigned)(pk & 0xffffffffu));
        }

        // MAC: partial[J] += sum_kk h[w*64+kk] * W[kk] — register-resident W, readlane h
        const unsigned hbits = __float_as_uint(hreg);
        float a0 = 0.f, a1 = 0.f, a2 = 0.f, a3 = 0.f;
#define BCAST(i) __uint_as_float(__builtin_amdgcn_readlane(hbits, (i)))
#define MACQ(q) do { \
        a0 = fmaf(BCAST(4*q+0), wv##q.x, a0); \
        a1 = fmaf(BCAST(4*q+1), wv##q.y, a1); \
        a2 = fmaf(BCAST(4*q+2), wv##q.z, a2); \
        a3 = fmaf(BCAST(4*q+3), wv##q.w, a3); } while (0)
        MACQ(0);  MACQ(1);  MACQ(2);  MACQ(3);
        MACQ(4);  MACQ(5);  MACQ(6);  MACQ(7);
        MACQ(8);  MACQ(9);  MACQ(10); MACQ(11);
        MACQ(12); MACQ(13); MACQ(14); MACQ(15);
#undef MACQ
#undef BCAST
        lds_part[p][w][lane] = (a0 + a1) + (a2 + a3);
        __syncthreads();   // the ONLY barrier per step

        if (tid < 64) {
            float s = pre_cur;
            #pragma unroll
            for (int q = 0; q < 8; ++q) s += lds_part[p][q][lane];
            // tanh(s) = 1 - 2/(e^{2s}+1); exp-based, ~2e-7 abs err, inf-safe both tails
            const float e  = __expf(2.0f * s);
            const float hv = 1.0f - 2.0f / (e + 1.0f);
            if (t + 1 < TT) {
                // publish FIRST: it's the cross-WG critical path
                const unsigned long long pk =
                    ((unsigned long long)(tagbase + (unsigned)(t + 1)) << 32)
                    | (unsigned long long)__float_as_uint(hv);
                __hip_atomic_store(hbc + ((p << 9) + J), pk,
                                   __ATOMIC_RELAXED, __HIP_MEMORY_SCOPE_AGENT);
                rowbase[(long)t * HH + J] = hv;            // h out (overwrites consumed pre)
                pre_cur = rowbase[(long)(t + 1) * HH + J]; // prefetch hides under next poll
            } else {
                rowbase[(long)t * HH + J] = hv;
                hTout[(c << 9) + J] = hv;                  // final hidden state
            }
        }
    }
}

extern "C" void kernel_launch(void* const* d_in, const int* in_sizes, int n_in,
                              void* d_out, int out_size, void* d_ws, size_t ws_size,
                              hipStream_t stream) {
    const float* x    = (const float*)d_in[0];
    const float* Wih0 = (const float*)d_in[1];
    const float* Whh0 = (const float*)d_in[2];
    const float* b0   = (const float*)d_in[3];
    const float* Wih1 = (const float*)d_in[4];
    const float* Whh1 = (const float*)d_in[5];
    const float* b1   = (const float*)d_in[6];

    float* out = (float*)d_out;                       // [B,T,H] main + [2,B,H] tail
    float* hT  = out + (size_t)BB * TT * HH;

    // ws: [0, 256K) = hb2 packed {tag|value} broadcast buffer, 32 chains x 2 x 512 x 8B
    unsigned long long* hb2 = (unsigned long long*)d_ws;
    // Clear tags every call: graph replays reuse ws un-poisoned, and a stale tag from
    // the previous replay would exactly match this replay's wanted tag.
    (void)hipMemsetAsync(d_ws, 0, BB * 2 * HH * sizeof(unsigned long long), stream);

    // 1) pre0 = x @ W_ih0 + b0   -> d_out main region (scratch)
    ih_gemm<256><<<dim3((BB * TT) / 32), dim3(256), 0, stream>>>(x, Wih0, b0, out);
    // 2) layer-0 recurrence, in-place pre0 -> h0; hT[0] tail  (tags 1..2047)
    rnn_recur<<<dim3(256), dim3(512), 0, stream>>>(Whh0, out, hT, hb2, 0u);
    // 3) pre1 = h0 @ W_ih1 + b1, in-place
    ih_gemm<512><<<dim3((BB * TT) / 32), dim3(256), 0, stream>>>(out, Wih1, b1, out);
    // 4) layer-1 recurrence, in-place pre1 -> h1 (final out); hT[1] tail (tags 4097..6143)
    rnn_recur<<<dim3(256), dim3(512), 0, stream>>>(Whh1, out, hT + BB * HH, hb2, 4096u);
}

// Round 9
// 4285.176 us; speedup vs baseline: 8.4351x; 1.3035x over previous
//
#include <hip/hip_runtime.h>
#include <math.h>

#define TT 2048
#define BB 32
#define HH 512

// ---------------- input-projection GEMM: OUT[r,:] = X[r,:]@W + bias ----------------
template<int K>
__global__ void __launch_bounds__(256)
ih_gemm(const float* X, const float* __restrict__ W,
        const float* __restrict__ bias, float* OUT)
{
    __shared__ float xt[32][K];
    const int wg  = (int)blockIdx.x;
    const int tid = (int)threadIdx.x;
    const long row0 = (long)wg * 32;

    {   // stage 32 rows of X (coalesced float4)
        const float4* Xv = (const float4*)(X + row0 * K);
        float4* xtv = (float4*)(&xt[0][0]);
        const int n4 = 8 * K;
        for (int i = tid; i < n4; i += 256) xtv[i] = Xv[i];
    }
    __syncthreads();

    const int j2 = tid * 2;
    float acc0[32], acc1[32];
    #pragma unroll
    for (int r = 0; r < 32; ++r) { acc0[r] = 0.f; acc1[r] = 0.f; }

    for (int k = 0; k < K; k += 4) {
        const float2 w0 = *(const float2*)&W[(k+0)*HH + j2];
        const float2 w1 = *(const float2*)&W[(k+1)*HH + j2];
        const float2 w2 = *(const float2*)&W[(k+2)*HH + j2];
        const float2 w3 = *(const float2*)&W[(k+3)*HH + j2];
        #pragma unroll
        for (int r = 0; r < 32; ++r) {
            const float4 xv = *(const float4*)&xt[r][k];
            acc0[r] += xv.x*w0.x + xv.y*w1.x + xv.z*w2.x + xv.w*w3.x;
            acc1[r] += xv.x*w0.y + xv.y*w1.y + xv.z*w2.y + xv.w*w3.y;
        }
    }
    const float2 bv = *(const float2*)&bias[j2];
    #pragma unroll
    for (int r = 0; r < 32; ++r) {
        float2 o; o.x = acc0[r] + bv.x; o.y = acc1[r] + bv.y;
        *(float2*)&OUT[(row0 + r) * HH + j2] = o;
    }
}

// ---------------- fused 2-layer persistent recurrence ----------------
// Round-5/8 topology (8 WGs/chain, wave=k-group, 1 poll/thread, fan-in 1 WG) proven
// correct & comm-optimal; round-8 proved the step is RTT-bound (VGPR 88, dur flat).
// This kernel time-multiplexes BOTH layers on the same WG set so layer-1's compute
// (C2) hides inside layer-0's publish->poll RTT window:
//   body(t): P3 poll h0[t]  ->  C1(t+1): Whh0-MAC+reduce+publish h0[t+1]  (critical)
//            P2 poll h1[t-1] (1-step slack, ~no spin)
//            C2(t): Wih1-MAC(h0[t]) + Whh1-MAC(h1[t-1]) + reduce -> h1[t] out+publish
// Sequential depth 2T -> T+1; GEMM1 and all h0 global traffic eliminated.
//
// Each thread pins 3 x 64 W values (Whh0/Wih1/Whh1 slices) as named float4 SSA vals;
// amdgpu_waves_per_eu(2,2) grants the 256-VGPR budget (proven necessary, round 7/8).
//
// Sync: 8B relaxed agent-scope {tag:32|f32:32} atomics, two buffers (hb0/hb1), each
// double-buffered by parity. Tag-chain overwrite safety re-derived for the fused
// schedule: all consumers of tag T complete (P3(t)/P2(t) precede their lds writes,
// which precede the publishes the overwriter transitively waits on) before overwrite.
// LDS: lds_a/lds_b parity double-buffered; 2 uniform __syncthreads per body; the
// round-4 distance-1/distance-2 WAR argument holds per buffer (>=2 barriers between
// same-parity reuse, reader is wave0 which passes those barriers after its reads).
static __device__ __forceinline__ float tanhx(float s) {
    const float e = __expf(2.0f * s);
    return 1.0f - 2.0f / (e + 1.0f);
}
static __device__ __forceinline__ void pub(unsigned long long* p, unsigned tag, float v) {
    __hip_atomic_store(p, ((unsigned long long)tag << 32) | (unsigned long long)__float_as_uint(v),
                       __ATOMIC_RELAXED, __HIP_MEMORY_SCOPE_AGENT);
}
static __device__ __forceinline__ float pollv(unsigned long long* p, unsigned want) {
    unsigned long long pk = __hip_atomic_load(p, __ATOMIC_RELAXED, __HIP_MEMORY_SCOPE_AGENT);
    while ((unsigned)(pk >> 32) != want)
        pk = __hip_atomic_load(p, __ATOMIC_RELAXED, __HIP_MEMORY_SCOPE_AGENT);
    return __uint_as_float((unsigned)(pk & 0xffffffffu));
}

__global__ void __attribute__((amdgpu_flat_work_group_size(512, 512),
                               amdgpu_waves_per_eu(2, 2)))
fused_recur(const float* __restrict__ Whh0, const float* __restrict__ Wih1,
            const float* __restrict__ Whh1, const float* __restrict__ b1,
            float* __restrict__ seq, float* __restrict__ hTout,
            unsigned long long* __restrict__ hb0, unsigned long long* __restrict__ hb1)
{
    __shared__ float lds_a[2][8][64];
    __shared__ float lds_b[2][8][64];
    const int bid  = (int)blockIdx.x;
    const int c    = bid & 31;      // chain; 8 slices of chain c share bid%8 (XCD-local if round-robin)
    const int x    = bid >> 5;      // col-slice 0..7
    const int tid  = (int)threadIdx.x;
    const int lane = tid & 63;
    const int w    = tid >> 6;      // wave id == k-group
    const int J    = (x << 6) + lane;
    const long wb  = (long)(w << 6) * HH + J;   // &M[(w*64+kk)*HH + J], kk stride HH

    // ---- three W slices, 48 named float4s (192 VGPRs), pinned ----
    float4 wa0,wa1,wa2,wa3,wa4,wa5,wa6,wa7,wa8,wa9,wa10,wa11,wa12,wa13,wa14,wa15;  // Whh0
    float4 wi0,wi1,wi2,wi3,wi4,wi5,wi6,wi7,wi8,wi9,wi10,wi11,wi12,wi13,wi14,wi15;  // Wih1
    float4 wh0,wh1,wh2,wh3,wh4,wh5,wh6,wh7,wh8,wh9,wh10,wh11,wh12,wh13,wh14,wh15;  // Whh1
#define LD1(P, M, q) do { \
        P##q.x = M[wb + (4*q+0)*HH]; P##q.y = M[wb + (4*q+1)*HH]; \
        P##q.z = M[wb + (4*q+2)*HH]; P##q.w = M[wb + (4*q+3)*HH]; } while (0)
#define LD16(P, M) do { LD1(P,M,0); LD1(P,M,1); LD1(P,M,2); LD1(P,M,3); \
        LD1(P,M,4); LD1(P,M,5); LD1(P,M,6); LD1(P,M,7); LD1(P,M,8); LD1(P,M,9); \
        LD1(P,M,10); LD1(P,M,11); LD1(P,M,12); LD1(P,M,13); LD1(P,M,14); LD1(P,M,15); } while (0)
    LD16(wa, Whh0); LD16(wi, Wih1); LD16(wh, Whh1);
#undef LD16
#undef LD1
#define PIN1(P, q) asm volatile("" : "+v"(P##q.x), "+v"(P##q.y), "+v"(P##q.z), "+v"(P##q.w))
#define PIN16(P) do { PIN1(P,0); PIN1(P,1); PIN1(P,2); PIN1(P,3); PIN1(P,4); PIN1(P,5); \
        PIN1(P,6); PIN1(P,7); PIN1(P,8); PIN1(P,9); PIN1(P,10); PIN1(P,11); PIN1(P,12); \
        PIN1(P,13); PIN1(P,14); PIN1(P,15); } while (0)
    PIN16(wa); PIN16(wi); PIN16(wh);
#undef PIN16
#undef PIN1

    unsigned long long* hbc0 = hb0 + c * (2 * HH);   // [2][512] packed {tag|val}
    unsigned long long* hbc1 = hb1 + c * (2 * HH);
    float* rowbase = seq + (long)c * TT * HH;        // pre0 in, h1 out (in-place)

    float pre_cur = 0.f, b1v = 0.f;
    if (tid < 64) { pre_cur = rowbase[J]; b1v = b1[J]; }

    // prologue: h0[0] = tanh(pre0[0] + 0); publish tag 1 (slot 0)
    if (tid < 64) {
        const float hv = tanhx(pre_cur);
        pub(hbc0 + J, 1u, hv);
        pre_cur = rowbase[HH + J];                   // pre0[1]
    }
    float h1reg = 0.f;

    for (int t = 0; t < TT; ++t) {
        // P3: poll h0[t] (tag t+1, slot t&1) — the one real RTT wait per super-step
        const float h0new = pollv(hbc0 + ((t & 1) << 9) + (w << 6) + lane, (unsigned)(t + 1));
        const unsigned h0bits = __float_as_uint(h0new);

        if (t + 1 < TT) {   // C1(t+1): layer-0 step — the critical chain
            float a0 = 0.f, a1 = 0.f, a2 = 0.f, a3 = 0.f;
#define BC0(i) __uint_as_float(__builtin_amdgcn_readlane(h0bits, (i)))
#define MACA(q) do { a0 = fmaf(BC0(4*q+0), wa##q.x, a0); a1 = fmaf(BC0(4*q+1), wa##q.y, a1); \
                     a2 = fmaf(BC0(4*q+2), wa##q.z, a2); a3 = fmaf(BC0(4*q+3), wa##q.w, a3); } while (0)
            MACA(0); MACA(1); MACA(2); MACA(3); MACA(4); MACA(5); MACA(6); MACA(7);
            MACA(8); MACA(9); MACA(10); MACA(11); MACA(12); MACA(13); MACA(14); MACA(15);
#undef MACA
            lds_a[(t + 1) & 1][w][lane] = (a0 + a1) + (a2 + a3);
            __syncthreads();
            if (tid < 64) {
                float s = pre_cur;
                #pragma unroll
                for (int q = 0; q < 8; ++q) s += lds_a[(t + 1) & 1][q][lane];
                const float hv = tanhx(s);
                pub(hbc0 + (((t + 1) & 1) << 9) + J, (unsigned)(t + 2), hv);  // publish ASAP
                if (t + 2 < TT) pre_cur = rowbase[(long)(t + 2) * HH + J];
                if (t + 1 == TT - 1) hTout[(c << 9) + J] = hv;                // hT layer 0
            }
        }

        // P2: poll h1[t-1] (tag t, slot (t-1)&1) — published a full super-step ago
        if (t > 0)
            h1reg = pollv(hbc1 + (((t - 1) & 1) << 9) + (w << 6) + lane, (unsigned)t);
        const unsigned h1bits = __float_as_uint(h1reg);

        // C2(t): layer-1 step — fills the next P3's RTT window
        {
            float a0 = 0.f, a1 = 0.f, a2 = 0.f, a3 = 0.f;
#define BC1(i) __uint_as_float(__builtin_amdgcn_readlane(h1bits, (i)))
#define MACI(q) do { a0 = fmaf(BC0(4*q+0), wi##q.x, a0); a1 = fmaf(BC0(4*q+1), wi##q.y, a1); \
                     a2 = fmaf(BC0(4*q+2), wi##q.z, a2); a3 = fmaf(BC0(4*q+3), wi##q.w, a3); } while (0)
#define MACH(q) do { a0 = fmaf(BC1(4*q+0), wh##q.x, a0); a1 = fmaf(BC1(4*q+1), wh##q.y, a1); \
                     a2 = fmaf(BC1(4*q+2), wh##q.z, a2); a3 = fmaf(BC1(4*q+3), wh##q.w, a3); } while (0)
            MACI(0); MACI(1); MACI(2); MACI(3); MACI(4); MACI(5); MACI(6); MACI(7);
            MACI(8); MACI(9); MACI(10); MACI(11); MACI(12); MACI(13); MACI(14); MACI(15);
            MACH(0); MACH(1); MACH(2); MACH(3); MACH(4); MACH(5); MACH(6); MACH(7);
            MACH(8); MACH(9); MACH(10); MACH(11); MACH(12); MACH(13); MACH(14); MACH(15);
#undef MACH
#undef MACI
#undef BC1
#undef BC0
            lds_b[t & 1][w][lane] = (a0 + a1) + (a2 + a3);
            __syncthreads();
            if (tid < 64) {
                float s2 = b1v;
                #pragma unroll
                for (int q = 0; q < 8; ++q) s2 += lds_b[t & 1][q][lane];
                const float h1v = tanhx(s2);
                rowbase[(long)t * HH + J] = h1v;                   // THE output (h1 seq)
                if (t + 1 < TT) pub(hbc1 + ((t & 1) << 9) + J, (unsigned)(t + 1), h1v);
                else hTout[(BB << 9) + (c << 9) + J] = h1v;        // hT layer 1
            }
        }
    }
}

extern "C" void kernel_launch(void* const* d_in, const int* in_sizes, int n_in,
                              void* d_out, int out_size, void* d_ws, size_t ws_size,
                              hipStream_t stream) {
    const float* x    = (const float*)d_in[0];
    const float* Wih0 = (const float*)d_in[1];
    const float* Whh0 = (const float*)d_in[2];
    const float* b0   = (const float*)d_in[3];
    const float* Wih1 = (const float*)d_in[4];
    const float* Whh1 = (const float*)d_in[5];
    const float* b1   = (const float*)d_in[6];

    float* out = (float*)d_out;                       // [B,T,H] (h1 seq) + [2,B,H] (hT)
    float* hT  = out + (size_t)BB * TT * HH;

    // ws: hb0 [32][2][512]x8B = 256K, hb1 same at +256K. memset both each call:
    // graph replays reuse ws un-poisoned and stale tags would alias wanted tags.
    unsigned long long* hb0 = (unsigned long long*)d_ws;
    unsigned long long* hb1 = hb0 + (size_t)BB * 2 * HH;
    (void)hipMemsetAsync(d_ws, 0, (size_t)2 * BB * 2 * HH * sizeof(unsigned long long), stream);

    // 1) pre0 = x @ W_ih0 + b0  -> d_out main region (consumed in-place by fused_recur)
    ih_gemm<256><<<dim3((BB * TT) / 32), dim3(256), 0, stream>>>(x, Wih0, b0, out);
    // 2) fused 2-layer recurrence: h1 seq -> d_out (in-place over pre0), hT tails
    fused_recur<<<dim3(256), dim3(512), 0, stream>>>(Whh0, Wih1, Whh1, b1,
                                                     out, hT, hb0, hb1);
}